// Round 6
// baseline (406.903 us; speedup 1.0000x reference)
//
#include <hip/hip_runtime.h>
#include <stdint.h>

#define DEVI __device__ __forceinline__

typedef __bf16 bf16x8 __attribute__((ext_vector_type(8)));
typedef float  floatx4 __attribute__((ext_vector_type(4)));

// B=8, S=2048, H=1024. M = B*S = 16384.
// ws: Q @0 (32MiB, pre-scaled log2e/32) | K @+32M | Vt @+64M ([8][1024 d][2048 k])
//     lvec @+96M (f32[16384]) | P @+96M+64K (bf16 [8][2048][2048]);
//     P region overlays Xb (32MiB) + Wt (6MiB), dead before P written.
//
// Round-10: r4 (4-phase uneven) and r5 (2-phase) both ~131us/GEMM -> barrier
// count is NOT the limiter. m201 (same geometry, 1563TF) differs in phase
// DISCIPLINE: 16-MFMA phases, <=8 reads/phase, coarse lgkmcnt(0) pinned after
// the barrier (MFMA cluster streams w/o interleaved waits). This round ports
// that exactly, with reads balanced 8/4/8/4 via a p4 pre-read of next tile's
// NH0 B-frags (b0), enabled by a SECOND counted vmcnt at p3-end.
//
// Ledger (per-wave loads, steady state; stage_half = 2 loads):
//   enter tile t: O=4 {AH0,BH0}(t+1)
//   p1 +2 AH1(t+1) -> 6      p2 +2 BH1(t+1) -> 8
//   p3 +2 AH0(t+2) -> 10; vmcnt(4)@p3-end retires {AH0,BH0,AH1}(t+1); SBAR
//     -> p4 may pre-read BH0(t+1) frags from bn; p1/p3(t+1) reads covered
//   p4 +2 BH0(t+2) -> 6;  vmcnt(4)@p4-end retires {BH1(t+1)}; SBAR
//     -> p2(t+1) read of BH1 covered. Invariant restored: O=4 {AH0,BH0}(t+2).
//   Tails: kt+2>=kI: p3-end vmcnt(2) (retires AH0,BH0,AH1(t+1)); p4-end
//   vmcnt(0). Last tile: no stages/pre-read; waits no-ops.
// WAR: every stage targets a region whose last ds_read completed >=2 barriers
// earlier (p3->bc-AH0 read@p1; p4->bc-BH0 read@p1; p1->bn-AH1 read@p3(t-1);
// p2->bn-BH1 read@p2(t-1)). Phase-head reads all covered by vmcnt+SBAR chain.
// Frag liveness peak 64 VGPR (af 32 + b0 16 + (bfr1|b0n) 16) — same as r5.
// (Kept: no 32x32 MFMA, no LDS-staged epilogue, no B-direct loads; Q carries
// log2e/32 so EPI2 uses raw v_exp_f32.)

DEVI unsigned short f2bf(float f) {
  union { float f; uint32_t u; } x; x.f = f;
  return (unsigned short)((x.u + 0x7fffu + ((x.u >> 16) & 1u)) >> 16);
}
DEVI float bf2f(unsigned short s) {
  union { uint32_t u; float f; } x; x.u = ((uint32_t)s) << 16;
  return x.f;
}

// ---------------- fused prep: X->bf16, 3x W transpose->bf16, lvec=0 ----------------
__global__ __launch_bounds__(256) void k_prep(
    const float* __restrict__ X, unsigned short* __restrict__ Xb,
    const float* __restrict__ Wq, const float* __restrict__ Wk,
    const float* __restrict__ Wv, unsigned short* __restrict__ Wt,
    float* __restrict__ lvec) {
  __shared__ float tile[64][65];
  int bx = blockIdx.x, t = threadIdx.x;
  if (bx < 16384) {                 // convert X: 4194304 float4 groups
    int i = bx * 256 + t;
    float4 v = ((const float4*)X)[i];
    ushort4 o;
    o.x = f2bf(v.x); o.y = f2bf(v.y); o.z = f2bf(v.z); o.w = f2bf(v.w);
    ((ushort4*)Xb)[i] = o;
  } else if (bx < 17152) {          // 3 x 256 transpose blocks
    int idx = bx - 16384;
    int sel = idx >> 8, b2 = idx & 255;
    const float* W = sel == 0 ? Wq : (sel == 1 ? Wk : Wv);
    unsigned short* Wo = Wt + ((size_t)sel << 20);
    int h0 = (b2 & 15) * 64, d0 = (b2 >> 4) * 64;
#pragma unroll
    for (int i = 0; i < 16; ++i) {
      int idx2 = i * 256 + t; int r = idx2 >> 6, c = idx2 & 63;
      tile[r][c] = W[(size_t)(h0 + r) * 1024 + d0 + c];
    }
    __syncthreads();
#pragma unroll
    for (int i = 0; i < 16; ++i) {
      int idx2 = i * 256 + t; int r = idx2 >> 6, c = idx2 & 63;
      Wo[(size_t)(d0 + r) * 1024 + h0 + c] = f2bf(tile[c][r]);
    }
  } else {                          // zero lvec (16384 f32)
    float4 z4 = {0.f, 0.f, 0.f, 0.f};
#pragma unroll
    for (int i = 0; i < 16; ++i) ((float4*)lvec)[i * 256 + t] = z4;
  }
}

// ---------------- async 16B global -> LDS ----------------
DEVI void gl_lds16(const unsigned short* gp, const unsigned short* lp) {
  __builtin_amdgcn_global_load_lds(
      (const __attribute__((address_space(1))) void*)gp,
      (__attribute__((address_space(3))) void*)lp, 16, 0, 0);
}

// Stage one half-tile from persistent streams; advance streams +128B.
#define STAGE_A(q, BUF)                                                       \
  do {                                                                        \
    gl_lds16(gA[q][0], AsF + (BUF) + dA[q][0]);                               \
    gl_lds16(gA[q][1], AsF + (BUF) + dA[q][1]);                               \
    gA[q][0] += 64; gA[q][1] += 64;                                           \
  } while (0)
#define STAGE_B(q, BUF)                                                       \
  do {                                                                        \
    gl_lds16(gB[q][0], BsF + (BUF) + dB[q][0]);                               \
    gl_lds16(gB[q][1], BsF + (BUF) + dB[q][1]);                               \
    gB[q][0] += 64; gB[q][1] += 64;                                           \
  } while (0)

// Fragment loads: base ptr + compile-time immediate only.
#define READ_A(MH)                                                            \
  _Pragma("unroll") for (int ms = 0; ms < 4; ++ms) {                          \
    af[0][ms] = *(const bf16x8*)(pA0 + (MH) * 8192 + ms * 2048);              \
    af[1][ms] = *(const bf16x8*)(pA1 + (MH) * 8192 + ms * 2048);              \
  }

// 16 MFMAs for one C-quadrant (caller wraps with setprio).
#define MFMA_Q(MH, NH, BSET)                                                  \
  _Pragma("unroll") for (int kk = 0; kk < 2; ++kk)                            \
  _Pragma("unroll") for (int ms = 0; ms < 4; ++ms)                            \
  _Pragma("unroll") for (int ns = 0; ns < 2; ++ns)                            \
    acc[(MH) * 4 + ms][(NH) * 2 + ns] =                                       \
        __builtin_amdgcn_mfma_f32_16x16x32_bf16(                              \
            af[kk][ms], BSET[kk][ns], acc[(MH) * 4 + ms][(NH) * 2 + ns],      \
            0, 0, 0);

#define PRIO1 __builtin_amdgcn_s_setprio(1)
#define PRIO0 __builtin_amdgcn_s_setprio(0)
#define WAITV4 asm volatile("s_waitcnt vmcnt(4)" ::: "memory")
#define WAITV2 asm volatile("s_waitcnt vmcnt(2)" ::: "memory")
#define WAITV0 asm volatile("s_waitcnt vmcnt(0)" ::: "memory")
#define SBAR __builtin_amdgcn_s_barrier()
// Coarse post-barrier wait: all frag reads landed, then MFMA cluster streams.
// sched_barrier keeps the cluster from hoisting above the wait (rule #18).
#define LGK0                                                                  \
  do {                                                                        \
    asm volatile("s_waitcnt lgkmcnt(0)" ::: "memory");                        \
    __builtin_amdgcn_sched_barrier(0);                                        \
  } while (0)

// ---------------- C = A * Bt^T  (both bf16 row-major, K-major rows) ----------------
// 256x256 tile, BK=64, 8 waves (2M x 4N, 128x64 each), 128KiB dbuf LDS.
// EPI: 4 = fused QKV (sel=blockIdx.y>>2): Q (x+b)*log2e/32, K x+b, V -> Vt[b][d][k]
//      2 = P = 2^S masked, bf16; atomic row sums -> lsum
//      3 = O = (P*V) * 1/lvec[row], f32
template <int EPI>
__global__ __launch_bounds__(512, 2) void k_gemm(
    const unsigned short* __restrict__ A, const unsigned short* __restrict__ Bt,
    void* __restrict__ Cv,
    const float* __restrict__ bias_q, const float* __restrict__ bias_k,
    const float* __restrict__ bias_v,
    const float* __restrict__ lvec, float* __restrict__ lsum,
    const int* __restrict__ mask,
    long aZ, long bZ, int ldA, int ldB, int kIters)
{
  // One buffer = 256x64 bf16 = 16384 ushorts (32KB); dbuf per operand.
  __shared__ __attribute__((aligned(16))) unsigned short AsF[2 * 256 * 64];
  __shared__ __attribute__((aligned(16))) unsigned short BsF[2 * 256 * 64];
  const int tid = threadIdx.x, w = tid >> 6, l = tid & 63;
  const int quad = l >> 4, l15 = l & 15;
  const int wr = w & 1, wc = w >> 1;           // 2M x 4N wave grid
  const int wm = wr * 128, wn = wc * 64;
  const int m0 = blockIdx.x * 256;
  const int z = blockIdx.z;

  int n0, sel = 0;
  if constexpr (EPI == 4) { sel = blockIdx.y >> 2; n0 = (blockIdx.y & 3) * 256; }
  else n0 = blockIdx.y * 256;

  const unsigned short* Az = A + (size_t)z * aZ;
  const unsigned short* Bz = (EPI == 4) ? (Bt + ((size_t)sel << 20))
                                        : (Bt + (size_t)z * bZ);

  // ---- hoisted stage streams ----
  const int lr = l >> 3, uu = (l & 7) ^ lr;    // stage swizzle (row bases %8==0)
  const unsigned short* gA[2][2]; const unsigned short* gB[2][2];
  int dA[2][2], dB[2][2];
#pragma unroll
  for (int q = 0; q < 2; ++q)
#pragma unroll
    for (int j = 0; j < 2; ++j) {
      int slot = w * 2 + j;
      int rA = (slot >> 3) * 128 + q * 64 + (slot & 7) * 8;
      int rB = (slot >> 2) * 64 + q * 32 + (slot & 3) * 8;
      gA[q][j] = Az + (size_t)(m0 + rA + lr) * ldA + uu * 8;
      gB[q][j] = Bz + (size_t)(n0 + rB + lr) * ldB + uu * 8;
      dA[q][j] = rA * 64; dB[q][j] = rB * 64;
    }

  // ---- hoisted fragment-read byte offsets (frag swizzle (rr&7)==l15&7) ----
  const int cc0 = quad ^ (l15 & 7), cc1 = cc0 ^ 4;
  const int aoffA0 = (wm + l15) * 128 + cc0 * 16;
  const int aoffA1 = (wm + l15) * 128 + cc1 * 16;
  const int aoffB0 = (wn + l15) * 128 + cc0 * 16;
  const int aoffB1 = (wn + l15) * 128 + cc1 * 16;

  floatx4 acc[8][4];
#pragma unroll
  for (int i = 0; i < 8; ++i)
#pragma unroll
    for (int j = 0; j < 4; ++j) { floatx4 zz = {0.f, 0.f, 0.f, 0.f}; acc[i][j] = zz; }

  // -------- prologue: tile0 full + AH0/BH0(1); then pre-read b0(tile0) -----
  STAGE_A(0, 0); STAGE_B(0, 0);            // AH0(0), BH0(0)
  STAGE_A(1, 0); STAGE_B(1, 0);            // AH1(0), BH1(0)
  if (kIters > 1) {
    STAGE_A(0, 16384); STAGE_B(0, 16384);  // AH0(1), BH0(1)
    WAITV4;                                 // retires tile0 (8 oldest)
  } else {
    WAITV0;
  }
  SBAR;                                     // all waves' tile0 in LDS

  bf16x8 b0[2][2];                          // NH0 B-frags, pre-held across tiles
  {
    const char* qB0 = (const char*)AsF;     // placate compiler; real base below
    (void)qB0;
    const char* rB0 = (const char*)BsF + aoffB0;
    const char* rB1 = (const char*)BsF + aoffB1;
    b0[0][0] = *(const bf16x8*)(rB0); b0[0][1] = *(const bf16x8*)(rB0 + 2048);
    b0[1][0] = *(const bf16x8*)(rB1); b0[1][1] = *(const bf16x8*)(rB1 + 2048);
  }

  // -------- main loop: 4 m201-style phases/K-tile, dual counted vmcnt ------
#pragma unroll 2
  for (int kt = 0; kt < kIters; ++kt) {
    const int ob = (kt & 1) ? 16384 : 0;   // current buffer (ushort offset)
    const int on = ob ^ 16384;             // next buffer
    const char* pA0 = (const char*)(AsF + ob) + aoffA0;
    const char* pA1 = (const char*)(AsF + ob) + aoffA1;
    const char* pB0 = (const char*)(BsF + ob) + aoffB0;
    const char* pB1 = (const char*)(BsF + ob) + aoffB1;
    bf16x8 af[2][4], bfr1[2][2], b0n[2][2];

    // ---- p1: read af0 (8); stage AH1(t+1)->bn; Q00 = af x b0 ----
    READ_A(0);
    if (kt + 1 < kIters) STAGE_A(1, on);
    SBAR; LGK0;
    PRIO1; MFMA_Q(0, 0, b0); PRIO0;
    SBAR;
    // ---- p2: read bfr1 (4); stage BH1(t+1)->bn; Q01 = af x bfr1 ----
    bfr1[0][0] = *(const bf16x8*)(pB0 + 4096);
    bfr1[0][1] = *(const bf16x8*)(pB0 + 4096 + 2048);
    bfr1[1][0] = *(const bf16x8*)(pB1 + 4096);
    bfr1[1][1] = *(const bf16x8*)(pB1 + 4096 + 2048);
    if (kt + 1 < kIters) STAGE_B(1, on);
    SBAR; LGK0;
    PRIO1; MFMA_Q(0, 1, bfr1); PRIO0;
    SBAR;
    // ---- p3: read af1 (8); stage AH0(t+2)->bc; Q11 = af x bfr1;
    //          vmcnt retires {AH0,BH0,AH1}(t+1) ----
    READ_A(1);
    if (kt + 2 < kIters) STAGE_A(0, ob);
    SBAR; LGK0;
    PRIO1; MFMA_Q(1, 1, bfr1); PRIO0;
    if (kt + 2 < kIters) { WAITV4; } else if (kt + 1 < kIters) { WAITV2; }
    SBAR;
    // ---- p4: pre-read b0n (4, from bn: tile t+1 NH0); stage BH0(t+2)->bc;
    //          Q10 = af x b0 (no new deps -> no coarse wait);
    //          vmcnt retires {BH1(t+1)} ----
    if (kt + 1 < kIters) {
      const char* qB0 = (const char*)(BsF + on) + aoffB0;
      const char* qB1 = (const char*)(BsF + on) + aoffB1;
      b0n[0][0] = *(const bf16x8*)(qB0); b0n[0][1] = *(const bf16x8*)(qB0 + 2048);
      b0n[1][0] = *(const bf16x8*)(qB1); b0n[1][1] = *(const bf16x8*)(qB1 + 2048);
    }
    if (kt + 2 < kIters) STAGE_B(0, ob);
    SBAR;
    PRIO1; MFMA_Q(1, 0, b0); PRIO0;
    if (kt + 2 < kIters) { WAITV4; } else { WAITV0; }
    SBAR;
    // rotate pre-read frags (SSA-renamed away under unroll)
    if (kt + 1 < kIters) {
      b0[0][0] = b0n[0][0]; b0[0][1] = b0n[0][1];
      b0[1][0] = b0n[1][0]; b0[1][1] = b0n[1][1];
    }
  }

  // epilogue: C/D layout col = lane&15, row = quad*4 + reg  [m89/m91]
  if constexpr (EPI == 4) {
    unsigned short* C = (unsigned short*)Cv + ((size_t)sel << 24);
    const float* bs = sel == 0 ? bias_q : (sel == 1 ? bias_k : bias_v);
    if (sel < 2) {
      // Q scale folds 1/sqrt(H)=1/32 AND log2(e) so EPI2 uses raw v_exp_f32.
      float sc = sel == 0 ? 0.045084439f : 1.0f;   // log2e/32
#pragma unroll
      for (int ns = 0; ns < 4; ++ns) {
        int n_g = n0 + wn + ns * 16 + l15;
        float bv = bs[n_g];
#pragma unroll
        for (int ms = 0; ms < 8; ++ms) {
          int mb = m0 + wm + ms * 16 + quad * 4;
#pragma unroll
          for (int r = 0; r < 4; ++r)
            C[(size_t)(mb + r) * 1024 + n_g] = f2bf((acc[ms][ns][r] + bv) * sc);
        }
      }
    } else {
      // V -> Vt[b][d][k]: the 4 r-values are CONSECUTIVE in k -> pack 8B stores
#pragma unroll
      for (int ns = 0; ns < 4; ++ns) {
        int n_g = n0 + wn + ns * 16 + l15;
        float bv = bs[n_g];
#pragma unroll
        for (int ms = 0; ms < 8; ++ms) {
          int m_g = m0 + wm + ms * 16 + quad * 4;   // r=0 element
          int bb = m_g >> 11, key = m_g & 2047;
          ushort4 pk;
          pk.x = f2bf(acc[ms][ns][0] + bv);
          pk.y = f2bf(acc[ms][ns][1] + bv);
          pk.z = f2bf(acc[ms][ns][2] + bv);
          pk.w = f2bf(acc[ms][ns][3] + bv);
          *(ushort4*)&C[((size_t)bb << 21) + ((size_t)n_g << 11) + key] = pk;
        }
      }
    }
  } else if constexpr (EPI == 2) {
    // P = 2^S (S pre-scaled by log2e; max-free: |S| small), masked; rowsums
    unsigned short* C = (unsigned short*)Cv + (size_t)z * 4194304;
    const int* mz = mask + z * 2048;
    float rowsum[8][4];
#pragma unroll
    for (int ms = 0; ms < 8; ++ms)
#pragma unroll
      for (int r = 0; r < 4; ++r) rowsum[ms][r] = 0.f;
#pragma unroll
    for (int ns = 0; ns < 4; ++ns) {
      int n_g = n0 + wn + ns * 16 + l15;
      int mv = mz[n_g];
#pragma unroll
      for (int ms = 0; ms < 8; ++ms) {
#pragma unroll
        for (int r = 0; r < 4; ++r) {
          int m_g = m0 + wm + ms * 16 + quad * 4 + r;
          float e;
          asm("v_exp_f32 %0, %1" : "=v"(e) : "v"(acc[ms][ns][r]));  // 2^x
          e = mv ? e : 0.f;
          unsigned short pb = f2bf(e);
          C[(size_t)m_g * 2048 + n_g] = pb;
          rowsum[ms][r] += bf2f(pb);
        }
      }
    }
#pragma unroll
    for (int ms = 0; ms < 8; ++ms) {
#pragma unroll
      for (int r = 0; r < 4; ++r) {
        float s = rowsum[ms][r];
#pragma unroll
        for (int off = 1; off < 16; off <<= 1) s += __shfl_xor(s, off);
        if (l15 == 0) {
          int m_g = m0 + wm + ms * 16 + quad * 4 + r;
          atomicAdd(&lsum[z * 2048 + m_g], s);
        }
      }
    }
  } else {  // EPI == 3: O = (P*V)/l
    float* C = (float*)Cv + (size_t)z * 2048 * 1024;
    const float* lz = lvec + z * 2048;
#pragma unroll
    for (int ms = 0; ms < 8; ++ms) {
#pragma unroll
      for (int r = 0; r < 4; ++r) {
        int m_g = m0 + wm + ms * 16 + quad * 4 + r;
        float lw = lz[m_g];
        float inv = lw > 0.f ? 1.f / lw : 0.f;
#pragma unroll
        for (int ns = 0; ns < 4; ++ns) {
          int n_g = n0 + wn + ns * 16 + l15;
          C[(size_t)m_g * 1024 + n_g] = acc[ms][ns][r] * inv;
        }
      }
    }
  }
}

extern "C" void kernel_launch(void* const* d_in, const int* in_sizes, int n_in,
                              void* d_out, int out_size, void* d_ws, size_t ws_size,
                              hipStream_t stream) {
  const float* X    = (const float*)d_in[0];
  const int*   mask = (const int*)d_in[1];
  const float* Wq   = (const float*)d_in[2];
  const float* bq   = (const float*)d_in[3];
  const float* Wk   = (const float*)d_in[4];
  const float* bk   = (const float*)d_in[5];
  const float* Wv   = (const float*)d_in[6];
  const float* bv   = (const float*)d_in[7];
  float* out = (float*)d_out;

  constexpr size_t SZ = (size_t)16384 * 1024;
  unsigned short* Q    = (unsigned short*)d_ws;      // Q|K|Vt contiguous (sel<<24)
  float*          lvec = (float*)(Q + 3 * SZ);
  unsigned short* P    = (unsigned short*)(lvec + 16384);
  unsigned short* Xb   = P;               // overlaid: dead before P written
  unsigned short* Wt   = Xb + SZ;         // 3 x [1024][1024] bf16
  unsigned short* Vt   = Q + 2 * SZ;

  // 1. prep: X->bf16, W->Wt (bf16, transposed), lvec=0
  k_prep<<<dim3(17153), 256, 0, stream>>>(X, Xb, Wq, Wk, Wv, Wt, lvec);

  // 2. fused QKV projection (12 n-strips: 4 Q, 4 K, 4 V)
  k_gemm<4><<<dim3(64, 12, 1), 512, 0, stream>>>(
      Xb, Wt, (void*)Q, bq, bk, bv, nullptr, nullptr, nullptr,
      0, 0, 1024, 1024, 16);

  // 3. P = 2^(Q K^T * log2e/32) masked + atomic row sums
  k_gemm<2><<<dim3(8, 8, 8), 512, 0, stream>>>(
      Q, Q + SZ, (void*)P, nullptr, nullptr, nullptr, nullptr, lvec, mask,
      2048 * 1024, 2048 * 1024, 1024, 1024, 16);

  // 4. O = (P V) / l  -> fp32 out
  k_gemm<3><<<dim3(8, 4, 8), 512, 0, stream>>>(
      P, Vt, (void*)out, nullptr, nullptr, nullptr, lvec, nullptr, nullptr,
      2048 * 2048, 1024 * 2048, 2048, 2048, 32);
}